// Round 4
// baseline (808.680 us; speedup 1.0000x reference)
//
#include <hip/hip_runtime.h>
#include <hip/hip_fp16.h>

// Two-layer cached GCN. Round 4: replace the random-scatter CSR fill
// (WRITE_SIZE was E*64B = 105 MB for a 6.4 MB array) with dst-bucket binning:
// edges -> 782 buckets of 128 nodes (packed 4B records), then per-bucket
// LDS-cursor fill into a contiguous ~16 KB col window. deg also comes from
// the bins (dense) instead of 1.6M random global atomics.

#define BKT_SHIFT 7
#define BKT_NODES 128

struct alignas(8) h4 { __half2 a, b; };

// ---------------- bucket histogram (LDS-privatized) ----------------
__global__ __launch_bounds__(256) void k_bincount(const int* __restrict__ dst,
                                                  int* __restrict__ bcnt, int E, int nbkt) {
    __shared__ int sh[1024];
    for (int i = threadIdx.x; i < nbkt; i += 256) sh[i] = 0;
    __syncthreads();
    for (long long e = (long long)blockIdx.x * 256 + threadIdx.x; e < E;
         e += (long long)gridDim.x * 256)
        atomicAdd(&sh[dst[e] >> BKT_SHIFT], 1);
    __syncthreads();
    for (int i = threadIdx.x; i < nbkt; i += 256)
        if (sh[i]) atomicAdd(&bcnt[i], sh[i]);
}

// ---------------- bucket scan (single block, nbkt <= 1024) ----------------
__global__ __launch_bounds__(1024) void k_bscan(const int* __restrict__ bcnt,
                                                int* __restrict__ bofs,
                                                int* __restrict__ bcur, int nbkt, int E) {
    __shared__ int sh[1024];
    int t = threadIdx.x;
    int v = (t < nbkt) ? bcnt[t] : 0;
    int x = v;
    sh[t] = x;
    __syncthreads();
    for (int o = 1; o < 1024; o <<= 1) {
        int y = (t >= o) ? sh[t - o] : 0;
        __syncthreads();
        x += y;
        sh[t] = x;
        __syncthreads();
    }
    if (t < nbkt) { bofs[t] = x - v; bcur[t] = x - v; }
    if (t == 0) bofs[nbkt] = E;
}

// ---------------- bin fill: recs[pos] = (dst_low << 17) | src ----------------
__global__ __launch_bounds__(256) void k_binfill(const int* __restrict__ src,
                                                 const int* __restrict__ dst,
                                                 int* __restrict__ bcur,
                                                 unsigned* __restrict__ recs, int E) {
    int e = blockIdx.x * 256 + threadIdx.x;
    if (e < E) {
        int d = dst[e];
        int b = d >> BKT_SHIFT;
        int pos = atomicAdd(&bcur[b], 1);
        recs[pos] = ((unsigned)(d & (BKT_NODES - 1)) << 17) | (unsigned)src[e];
    }
}

// ---------------- per-node degree from bins (dense) ----------------
__global__ __launch_bounds__(256) void k_deg_bins(const unsigned* __restrict__ recs,
                                                  const int* __restrict__ bofs,
                                                  int* __restrict__ deg, int n) {
    __shared__ int cnt[BKT_NODES];
    const int b = blockIdx.x, t = threadIdx.x;
    if (t < BKT_NODES) cnt[t] = 0;
    __syncthreads();
    const int beg = bofs[b], end = bofs[b + 1];
    for (int j = beg + t; j < end; j += 256)
        atomicAdd(&cnt[recs[j] >> 17], 1);
    __syncthreads();
    const int d0 = b << BKT_SHIFT;
    if (t < BKT_NODES && d0 + t < n) deg[d0 + t] = cnt[t];
}

// ---------------- exclusive scan over nodes (3 kernels) + dinv ----------------
__global__ void k_scan1(const int* __restrict__ deg, float* __restrict__ dinv,
                        int* __restrict__ ofs, int* __restrict__ sums, int n) {
    __shared__ int sh[256];
    const int t = threadIdx.x;
    const int i = blockIdx.x * 256 + t;
    int v = (i < n) ? deg[i] : 0;
    if (i < n) dinv[i] = rsqrtf((float)v + 1.0f);  // +1 self-loop
    int x = v;
    sh[t] = x;
    __syncthreads();
    for (int o = 1; o < 256; o <<= 1) {
        int y = (t >= o) ? sh[t - o] : 0;
        __syncthreads();
        x += y;
        sh[t] = x;
        __syncthreads();
    }
    if (i < n) ofs[i] = x - v;
    if (t == 255) sums[blockIdx.x] = x;
}

__global__ void k_scan2(int* __restrict__ sums, int nb) {
    __shared__ int sh[512];
    const int t = threadIdx.x;
    int carry = 0;
    for (int base = 0; base < nb; base += 512) {
        int i = base + t;
        int v = (i < nb) ? sums[i] : 0;
        int x = v;
        sh[t] = x;
        __syncthreads();
        for (int o = 1; o < 512; o <<= 1) {
            int y = (t >= o) ? sh[t - o] : 0;
            __syncthreads();
            x += y;
            sh[t] = x;
            __syncthreads();
        }
        if (i < nb) sums[i] = x - v + carry;
        int tot = sh[511];
        __syncthreads();
        carry += tot;
    }
}

__global__ void k_scan3(int* __restrict__ ofs, const int* __restrict__ sums, int n, int E) {
    int i = blockIdx.x * 256 + threadIdx.x;
    if (i < n) ofs[i] += sums[blockIdx.x];
    if (i == 0) ofs[n] = E;
}

// ---------------- CSR fill from bins: col window per bucket is contiguous ----------------
__global__ __launch_bounds__(256) void k_fill_bins(const unsigned* __restrict__ recs,
                                                   const int* __restrict__ bofs,
                                                   const int* __restrict__ ofs,
                                                   int* __restrict__ col, int n) {
    __shared__ int cur[BKT_NODES];
    const int b = blockIdx.x, t = threadIdx.x;
    const int d0 = b << BKT_SHIFT;
    if (t < BKT_NODES) cur[t] = (d0 + t < n) ? ofs[d0 + t] : 0;
    __syncthreads();
    const int beg = bofs[b], end = bofs[b + 1];
    for (int j = beg + t; j < end; j += 256) {
        unsigned r = recs[j];
        int p = atomicAdd(&cur[r >> 17], 1);
        col[p] = (int)(r & 0x1FFFF);
    }
}

// ---------------- GEMM: ts[N x 128](fp16) = dinv[row] * ((relu?)in @ W) ----------------
__global__ __launch_bounds__(256, 2) void k_gemm(const float* __restrict__ in,
                                                 const float* __restrict__ W,
                                                 const float* __restrict__ dinv,
                                                 __half* __restrict__ out,
                                                 int nrows_total, int relu_in) {
    __shared__ float Wl[64 * 128];  // 32 KB
    __shared__ float Xl[32 * 128];  // 16 KB
    const int t = threadIdx.x;
    const long long row0 = (long long)blockIdx.x * 32;
    int nr = nrows_total - (int)row0;
    if (nr > 32) nr = 32;

    for (int i = t * 4; i < nr * 128; i += 256 * 4) {
        float4 v = *(const float4*)&in[row0 * 128 + i];
        if (relu_in) {
            v.x = fmaxf(v.x, 0.f); v.y = fmaxf(v.y, 0.f);
            v.z = fmaxf(v.z, 0.f); v.w = fmaxf(v.w, 0.f);
        }
        *(float4*)&Xl[i] = v;
    }

    const int c4 = t & 31;
    const int rg = t >> 5;
    float4 acc[4];
#pragma unroll
    for (int r = 0; r < 4; r++) acc[r] = make_float4(0.f, 0.f, 0.f, 0.f);

    for (int half = 0; half < 2; half++) {
        __syncthreads();
        for (int i = t * 4; i < 64 * 128; i += 256 * 4)
            *(float4*)&Wl[i] = *(const float4*)&W[half * 64 * 128 + i];
        __syncthreads();
#pragma unroll 4
        for (int k4 = 0; k4 < 16; k4++) {
            float4 wv0 = *(float4*)&Wl[(k4 * 4 + 0) * 128 + c4 * 4];
            float4 wv1 = *(float4*)&Wl[(k4 * 4 + 1) * 128 + c4 * 4];
            float4 wv2 = *(float4*)&Wl[(k4 * 4 + 2) * 128 + c4 * 4];
            float4 wv3 = *(float4*)&Wl[(k4 * 4 + 3) * 128 + c4 * 4];
#pragma unroll
            for (int r = 0; r < 4; r++) {
                float4 xv = *(float4*)&Xl[(rg + r * 8) * 128 + half * 64 + k4 * 4];
                acc[r].x += xv.x * wv0.x + xv.y * wv1.x + xv.z * wv2.x + xv.w * wv3.x;
                acc[r].y += xv.x * wv0.y + xv.y * wv1.y + xv.z * wv2.y + xv.w * wv3.y;
                acc[r].z += xv.x * wv0.z + xv.y * wv1.z + xv.z * wv2.z + xv.w * wv3.z;
                acc[r].w += xv.x * wv0.w + xv.y * wv1.w + xv.z * wv2.w + xv.w * wv3.w;
            }
        }
    }

#pragma unroll
    for (int r = 0; r < 4; r++) {
        int rr = rg + r * 8;
        if (rr < nr) {
            float dv = dinv[row0 + rr];
            h4 o;
            o.a = __float22half2_rn(make_float2(acc[r].x * dv, acc[r].y * dv));
            o.b = __float22half2_rn(make_float2(acc[r].z * dv, acc[r].w * dv));
            *(h4*)&out[(row0 + rr) * 128 + c4 * 4] = o;
        }
    }
}

// ---------------- CSR aggregation: out[d] = bias + dinv[d] * (ts[d] + sum_j ts[col[j]]) ----------------
__global__ __launch_bounds__(256) void k_agg_csr(const int* __restrict__ ofs,
                                                 const int* __restrict__ col,
                                                 const float* __restrict__ dinv,
                                                 const __half* __restrict__ ts,
                                                 const float* __restrict__ bias,
                                                 float* __restrict__ out, int n) {
    int gid = blockIdx.x * 256 + threadIdx.x;
    int row = gid >> 5;
    int lane = gid & 31;
    if (row >= n) return;

    float dd = dinv[row];
    int beg = ofs[row];
    int end = ofs[row + 1];

    h4 sv = *(const h4*)&ts[(long long)row * 128 + lane * 4];
    float2 s0 = __half22float2(sv.a);
    float2 s1 = __half22float2(sv.b);
    float4 acc = make_float4(s0.x, s0.y, s1.x, s1.y);

    int j = beg;
    for (; j + 1 < end; j += 2) {
        int sA = col[j];
        int sB = col[j + 1];
        h4 vA = *(const h4*)&ts[(long long)sA * 128 + lane * 4];
        h4 vB = *(const h4*)&ts[(long long)sB * 128 + lane * 4];
        float2 a0 = __half22float2(vA.a), a1 = __half22float2(vA.b);
        float2 b0 = __half22float2(vB.a), b1 = __half22float2(vB.b);
        acc.x += a0.x + b0.x;
        acc.y += a0.y + b0.y;
        acc.z += a1.x + b1.x;
        acc.w += a1.y + b1.y;
    }
    if (j < end) {
        int s = col[j];
        h4 v = *(const h4*)&ts[(long long)s * 128 + lane * 4];
        float2 a0 = __half22float2(v.a), a1 = __half22float2(v.b);
        acc.x += a0.x;
        acc.y += a0.y;
        acc.z += a1.x;
        acc.w += a1.y;
    }

    float4 bv = *(const float4*)&bias[lane * 4];
    float4 o;
    o.x = bv.x + dd * acc.x;
    o.y = bv.y + dd * acc.y;
    o.z = bv.z + dd * acc.z;
    o.w = bv.w + dd * acc.w;
    *(float4*)&out[(long long)row * 128 + lane * 4] = o;
}

extern "C" void kernel_launch(void* const* d_in, const int* in_sizes, int n_in,
                              void* d_out, int out_size, void* d_ws, size_t ws_size,
                              hipStream_t stream) {
    const int N = in_sizes[0] / 128;
    const int E = in_sizes[1] / 2;
    const float* x  = (const float*)d_in[0];
    const int*   ei = (const int*)d_in[1];
    const float* W1 = (const float*)d_in[2];
    const float* b1 = (const float*)d_in[3];
    const float* W2 = (const float*)d_in[4];
    const float* b2 = (const float*)d_in[5];

    const int* src = ei;
    const int* dst = ei + E;

    const int nb_n  = (N + 255) / 256;
    const int NBKT  = (N + BKT_NODES - 1) / BKT_NODES;  // 782 for N=100000

    // ---- workspace layout (t first: 16B-aligned) ----
    __half*   t    = (__half*)d_ws;                            // N*128 halves
    float*    dinv = (float*)((char*)d_ws + (size_t)N * 256);  // N
    int*      ofs  = (int*)(dinv + N);                         // N+1
    int*      deg  = ofs + N + 1;                              // N
    int*      sums = deg + N;                                  // nb_n (padded)
    unsigned* recs = (unsigned*)(sums + ((nb_n + 255) & ~255));// E
    int*      col  = (int*)(recs + E);                         // E
    int*      bofs = col + E;                                  // NBKT+1
    int*      bcur = bofs + NBKT + 1;                          // NBKT
    int*      bcnt = bcur + NBKT;                              // NBKT

    float* h   = (float*)d_out;
    float* out = (float*)d_out;

    const int nb_e = (E + 255) / 256;
    const int nb_g = (N + 31) / 32;
    const int nb_a = (int)(((long long)N * 32 + 255) / 256);

    // ---- binning + CSR build (once; reused by both layers) ----
    hipMemsetAsync(bcnt, 0, (size_t)NBKT * 4, stream);
    k_bincount<<<512, 256, 0, stream>>>(dst, bcnt, E, NBKT);
    k_bscan<<<1, 1024, 0, stream>>>(bcnt, bofs, bcur, NBKT, E);
    k_binfill<<<nb_e, 256, 0, stream>>>(src, dst, bcur, recs, E);
    k_deg_bins<<<NBKT, 256, 0, stream>>>(recs, bofs, deg, N);
    k_scan1<<<nb_n, 256, 0, stream>>>(deg, dinv, ofs, sums, N);
    k_scan2<<<1, 512, 0, stream>>>(sums, nb_n);
    k_scan3<<<nb_n, 256, 0, stream>>>(ofs, sums, N, E);
    k_fill_bins<<<NBKT, 256, 0, stream>>>(recs, bofs, ofs, col, N);

    // ---- layer 1 ----
    k_gemm<<<nb_g, 256, 0, stream>>>(x, W1, dinv, t, N, 0);
    k_agg_csr<<<nb_a, 256, 0, stream>>>(ofs, col, dinv, t, b1, h, N);

    // ---- layer 2 (relu fused into GEMM's X staging) ----
    k_gemm<<<nb_g, 256, 0, stream>>>(h, W2, dinv, t, N, 1);
    k_agg_csr<<<nb_a, 256, 0, stream>>>(ofs, col, dinv, t, b2, out, N);
}

// Round 5
// 450.151 us; speedup vs baseline: 1.7965x; 1.7965x over previous
//
#include <hip/hip_runtime.h>
#include <hip/hip_fp16.h>

// Two-layer cached GCN. Round 5: fix the bucket-binning fill's atomic
// contention (782 hot cursors x ~2045 serialized RMWs each = 377us) with
// bulk reservation: per 8192-edge chunk, stage records in LDS, LDS-histogram,
// ONE global atomicAdd per non-empty bucket per chunk to reserve a span,
// then scatter via LDS cursors. ~150K global atomics instead of 1.6M.

#define BKT_SHIFT 7
#define BKT_NODES 128
#define CH 8192
#define MAXBKT 1024

struct alignas(8) h4 { __half2 a, b; };

__global__ __launch_bounds__(256) void k_bincount(const int* __restrict__ dst,
                                                  int* __restrict__ bcnt, int E, int nbkt) {
    __shared__ int sh[MAXBKT];
    for (int i = threadIdx.x; i < nbkt; i += 256) sh[i] = 0;
    __syncthreads();
    for (long long e = (long long)blockIdx.x * 256 + threadIdx.x; e < E;
         e += (long long)gridDim.x * 256)
        atomicAdd(&sh[dst[e] >> BKT_SHIFT], 1);
    __syncthreads();
    for (int i = threadIdx.x; i < nbkt; i += 256)
        if (sh[i]) atomicAdd(&bcnt[i], sh[i]);
}

__global__ __launch_bounds__(1024) void k_bscan(const int* __restrict__ bcnt,
                                                int* __restrict__ bofs,
                                                int* __restrict__ bcur, int nbkt, int E) {
    __shared__ int sh[1024];
    int t = threadIdx.x;
    int v = (t < nbkt) ? bcnt[t] : 0;
    int x = v;
    sh[t] = x;
    __syncthreads();
    for (int o = 1; o < 1024; o <<= 1) {
        int y = (t >= o) ? sh[t - o] : 0;
        __syncthreads();
        x += y;
        sh[t] = x;
        __syncthreads();
    }
    if (t < nbkt) { bofs[t] = x - v; bcur[t] = x - v; }
    if (t == 0) bofs[nbkt] = E;
}

// bulk-reservation bin fill
__global__ __launch_bounds__(256) void k_binfill(const int* __restrict__ src,
                                                 const int* __restrict__ dst,
                                                 int* __restrict__ bcur,
                                                 unsigned* __restrict__ recs,
                                                 int E, int nbkt) {
    __shared__ unsigned stage[CH];          // 32 KB: packed (dst_low<<17)|src
    __shared__ unsigned short stageb[CH];   // 16 KB: bucket id per staged edge
    __shared__ int cnt[MAXBKT];             // 4 KB
    __shared__ int base[MAXBKT];            // 4 KB
    const int t = threadIdx.x;
    const long long c0 = (long long)blockIdx.x * CH;

    for (int i = t; i < nbkt; i += 256) cnt[i] = 0;
    __syncthreads();

    // phase A: load+pack+stage+histogram (LDS atomics)
    for (int k = 0; k < CH / 256; k++) {
        int i = k * 256 + t;
        long long e = c0 + i;
        if (e < E) {
            int d = dst[e];
            int b = d >> BKT_SHIFT;
            stage[i] = ((unsigned)(d & (BKT_NODES - 1)) << 17) | (unsigned)src[e];
            stageb[i] = (unsigned short)b;
            atomicAdd(&cnt[b], 1);
        }
    }
    __syncthreads();

    // phase B: one global reservation per non-empty bucket; reset cnt for reuse
    for (int i = t; i < nbkt; i += 256) {
        int c = cnt[i];
        base[i] = c ? atomicAdd(&bcur[i], c) : 0;
        cnt[i] = 0;
    }
    __syncthreads();

    // phase C: scatter from LDS via LDS cursors
    for (int k = 0; k < CH / 256; k++) {
        int i = k * 256 + t;
        if (c0 + i < E) {
            int b = stageb[i];
            int p = base[b] + atomicAdd(&cnt[b], 1);
            recs[p] = stage[i];
        }
    }
}

__global__ __launch_bounds__(256) void k_deg_bins(const unsigned* __restrict__ recs,
                                                  const int* __restrict__ bofs,
                                                  int* __restrict__ deg, int n) {
    __shared__ int cnt[BKT_NODES];
    const int b = blockIdx.x, t = threadIdx.x;
    if (t < BKT_NODES) cnt[t] = 0;
    __syncthreads();
    const int beg = bofs[b], end = bofs[b + 1];
    for (int j = beg + t; j < end; j += 256)
        atomicAdd(&cnt[recs[j] >> 17], 1);
    __syncthreads();
    const int d0 = b << BKT_SHIFT;
    if (t < BKT_NODES && d0 + t < n) deg[d0 + t] = cnt[t];
}

__global__ void k_scan1(const int* __restrict__ deg, float* __restrict__ dinv,
                        int* __restrict__ ofs, int* __restrict__ sums, int n) {
    __shared__ int sh[256];
    const int t = threadIdx.x;
    const int i = blockIdx.x * 256 + t;
    int v = (i < n) ? deg[i] : 0;
    if (i < n) dinv[i] = rsqrtf((float)v + 1.0f);
    int x = v;
    sh[t] = x;
    __syncthreads();
    for (int o = 1; o < 256; o <<= 1) {
        int y = (t >= o) ? sh[t - o] : 0;
        __syncthreads();
        x += y;
        sh[t] = x;
        __syncthreads();
    }
    if (i < n) ofs[i] = x - v;
    if (t == 255) sums[blockIdx.x] = x;
}

__global__ void k_scan2(int* __restrict__ sums, int nb) {
    __shared__ int sh[512];
    const int t = threadIdx.x;
    int carry = 0;
    for (int base = 0; base < nb; base += 512) {
        int i = base + t;
        int v = (i < nb) ? sums[i] : 0;
        int x = v;
        sh[t] = x;
        __syncthreads();
        for (int o = 1; o < 512; o <<= 1) {
            int y = (t >= o) ? sh[t - o] : 0;
            __syncthreads();
            x += y;
            sh[t] = x;
            __syncthreads();
        }
        if (i < nb) sums[i] = x - v + carry;
        int tot = sh[511];
        __syncthreads();
        carry += tot;
    }
}

__global__ void k_scan3(int* __restrict__ ofs, const int* __restrict__ sums, int n, int E) {
    int i = blockIdx.x * 256 + threadIdx.x;
    if (i < n) ofs[i] += sums[blockIdx.x];
    if (i == 0) ofs[n] = E;
}

__global__ __launch_bounds__(256) void k_fill_bins(const unsigned* __restrict__ recs,
                                                   const int* __restrict__ bofs,
                                                   const int* __restrict__ ofs,
                                                   int* __restrict__ col, int n) {
    __shared__ int cur[BKT_NODES];
    const int b = blockIdx.x, t = threadIdx.x;
    const int d0 = b << BKT_SHIFT;
    if (t < BKT_NODES) cur[t] = (d0 + t < n) ? ofs[d0 + t] : 0;
    __syncthreads();
    const int beg = bofs[b], end = bofs[b + 1];
    for (int j = beg + t; j < end; j += 256) {
        unsigned r = recs[j];
        int p = atomicAdd(&cur[r >> 17], 1);
        col[p] = (int)(r & 0x1FFFF);
    }
}

__global__ __launch_bounds__(256, 2) void k_gemm(const float* __restrict__ in,
                                                 const float* __restrict__ W,
                                                 const float* __restrict__ dinv,
                                                 __half* __restrict__ out,
                                                 int nrows_total, int relu_in) {
    __shared__ float Wl[64 * 128];
    __shared__ float Xl[32 * 128];
    const int t = threadIdx.x;
    const long long row0 = (long long)blockIdx.x * 32;
    int nr = nrows_total - (int)row0;
    if (nr > 32) nr = 32;

    for (int i = t * 4; i < nr * 128; i += 256 * 4) {
        float4 v = *(const float4*)&in[row0 * 128 + i];
        if (relu_in) {
            v.x = fmaxf(v.x, 0.f); v.y = fmaxf(v.y, 0.f);
            v.z = fmaxf(v.z, 0.f); v.w = fmaxf(v.w, 0.f);
        }
        *(float4*)&Xl[i] = v;
    }

    const int c4 = t & 31;
    const int rg = t >> 5;
    float4 acc[4];
#pragma unroll
    for (int r = 0; r < 4; r++) acc[r] = make_float4(0.f, 0.f, 0.f, 0.f);

    for (int half = 0; half < 2; half++) {
        __syncthreads();
        for (int i = t * 4; i < 64 * 128; i += 256 * 4)
            *(float4*)&Wl[i] = *(const float4*)&W[half * 64 * 128 + i];
        __syncthreads();
#pragma unroll 4
        for (int k4 = 0; k4 < 16; k4++) {
            float4 wv0 = *(float4*)&Wl[(k4 * 4 + 0) * 128 + c4 * 4];
            float4 wv1 = *(float4*)&Wl[(k4 * 4 + 1) * 128 + c4 * 4];
            float4 wv2 = *(float4*)&Wl[(k4 * 4 + 2) * 128 + c4 * 4];
            float4 wv3 = *(float4*)&Wl[(k4 * 4 + 3) * 128 + c4 * 4];
#pragma unroll
            for (int r = 0; r < 4; r++) {
                float4 xv = *(float4*)&Xl[(rg + r * 8) * 128 + half * 64 + k4 * 4];
                acc[r].x += xv.x * wv0.x + xv.y * wv1.x + xv.z * wv2.x + xv.w * wv3.x;
                acc[r].y += xv.x * wv0.y + xv.y * wv1.y + xv.z * wv2.y + xv.w * wv3.y;
                acc[r].z += xv.x * wv0.z + xv.y * wv1.z + xv.z * wv2.z + xv.w * wv3.z;
                acc[r].w += xv.x * wv0.w + xv.y * wv1.w + xv.z * wv2.w + xv.w * wv3.w;
            }
        }
    }

#pragma unroll
    for (int r = 0; r < 4; r++) {
        int rr = rg + r * 8;
        if (rr < nr) {
            float dv = dinv[row0 + rr];
            h4 o;
            o.a = __float22half2_rn(make_float2(acc[r].x * dv, acc[r].y * dv));
            o.b = __float22half2_rn(make_float2(acc[r].z * dv, acc[r].w * dv));
            *(h4*)&out[(row0 + rr) * 128 + c4 * 4] = o;
        }
    }
}

__global__ __launch_bounds__(256) void k_agg_csr(const int* __restrict__ ofs,
                                                 const int* __restrict__ col,
                                                 const float* __restrict__ dinv,
                                                 const __half* __restrict__ ts,
                                                 const float* __restrict__ bias,
                                                 float* __restrict__ out, int n) {
    int gid = blockIdx.x * 256 + threadIdx.x;
    int row = gid >> 5;
    int lane = gid & 31;
    if (row >= n) return;

    float dd = dinv[row];
    int beg = ofs[row];
    int end = ofs[row + 1];

    h4 sv = *(const h4*)&ts[(long long)row * 128 + lane * 4];
    float2 s0 = __half22float2(sv.a);
    float2 s1 = __half22float2(sv.b);
    float4 acc = make_float4(s0.x, s0.y, s1.x, s1.y);

    int j = beg;
    for (; j + 1 < end; j += 2) {
        int sA = col[j];
        int sB = col[j + 1];
        h4 vA = *(const h4*)&ts[(long long)sA * 128 + lane * 4];
        h4 vB = *(const h4*)&ts[(long long)sB * 128 + lane * 4];
        float2 a0 = __half22float2(vA.a), a1 = __half22float2(vA.b);
        float2 b0 = __half22float2(vB.a), b1 = __half22float2(vB.b);
        acc.x += a0.x + b0.x;
        acc.y += a0.y + b0.y;
        acc.z += a1.x + b1.x;
        acc.w += a1.y + b1.y;
    }
    if (j < end) {
        int s = col[j];
        h4 v = *(const h4*)&ts[(long long)s * 128 + lane * 4];
        float2 a0 = __half22float2(v.a), a1 = __half22float2(v.b);
        acc.x += a0.x;
        acc.y += a0.y;
        acc.z += a1.x;
        acc.w += a1.y;
    }

    float4 bv = *(const float4*)&bias[lane * 4];
    float4 o;
    o.x = bv.x + dd * acc.x;
    o.y = bv.y + dd * acc.y;
    o.z = bv.z + dd * acc.z;
    o.w = bv.w + dd * acc.w;
    *(float4*)&out[(long long)row * 128 + lane * 4] = o;
}

extern "C" void kernel_launch(void* const* d_in, const int* in_sizes, int n_in,
                              void* d_out, int out_size, void* d_ws, size_t ws_size,
                              hipStream_t stream) {
    const int N = in_sizes[0] / 128;
    const int E = in_sizes[1] / 2;
    const float* x  = (const float*)d_in[0];
    const int*   ei = (const int*)d_in[1];
    const float* W1 = (const float*)d_in[2];
    const float* b1 = (const float*)d_in[3];
    const float* W2 = (const float*)d_in[4];
    const float* b2 = (const float*)d_in[5];

    const int* src = ei;
    const int* dst = ei + E;

    const int nb_n  = (N + 255) / 256;
    const int NBKT  = (N + BKT_NODES - 1) / BKT_NODES;

    __half*   t    = (__half*)d_ws;
    float*    dinv = (float*)((char*)d_ws + (size_t)N * 256);
    int*      ofs  = (int*)(dinv + N);
    int*      deg  = ofs + N + 1;
    int*      sums = deg + N;
    unsigned* recs = (unsigned*)(sums + ((nb_n + 255) & ~255));
    int*      col  = (int*)(recs + E);
    int*      bofs = col + E;
    int*      bcur = bofs + NBKT + 1;
    int*      bcnt = bcur + NBKT;

    float* h   = (float*)d_out;
    float* out = (float*)d_out;

    const int nb_g = (N + 31) / 32;
    const int nb_a = (int)(((long long)N * 32 + 255) / 256);
    const int nb_c = (int)(((long long)E + CH - 1) / CH);

    hipMemsetAsync(bcnt, 0, (size_t)NBKT * 4, stream);
    k_bincount<<<256, 256, 0, stream>>>(dst, bcnt, E, NBKT);
    k_bscan<<<1, 1024, 0, stream>>>(bcnt, bofs, bcur, NBKT, E);
    k_binfill<<<nb_c, 256, 0, stream>>>(src, dst, bcur, recs, E, NBKT);
    k_deg_bins<<<NBKT, 256, 0, stream>>>(recs, bofs, deg, N);
    k_scan1<<<nb_n, 256, 0, stream>>>(deg, dinv, ofs, sums, N);
    k_scan2<<<1, 512, 0, stream>>>(sums, nb_n);
    k_scan3<<<nb_n, 256, 0, stream>>>(ofs, sums, N, E);
    k_fill_bins<<<NBKT, 256, 0, stream>>>(recs, bofs, ofs, col, N);

    k_gemm<<<nb_g, 256, 0, stream>>>(x, W1, dinv, t, N, 0);
    k_agg_csr<<<nb_a, 256, 0, stream>>>(ofs, col, dinv, t, b1, h, N);

    k_gemm<<<nb_g, 256, 0, stream>>>(h, W2, dinv, t, N, 1);
    k_agg_csr<<<nb_a, 256, 0, stream>>>(ofs, col, dinv, t, b2, out, N);
}

// Round 6
// 345.779 us; speedup vs baseline: 2.3387x; 1.3018x over previous
//
#include <hip/hip_runtime.h>

// Two-layer cached GCN. Round 6: (a) GEMMs moved from fp32 vector-ALU to
// fp16 MFMA (mfma_f32_16x16x32_f16, fp32 accum) with pre-transposed fp16 W
// and padded LDS (row pad +8 halves kills the 16-way fragment-read conflict);
// (b) agg gather unrolled x4 for more outstanding loads (latency-bound).

#define BKT_SHIFT 7
#define BKT_NODES 128
#define CH 8192
#define MAXBKT 1024

typedef _Float16 half4v __attribute__((ext_vector_type(4)));
typedef _Float16 half8v __attribute__((ext_vector_type(8)));
typedef float float4v __attribute__((ext_vector_type(4)));

// ---------------- bucket histogram (LDS-privatized) ----------------
__global__ __launch_bounds__(256) void k_bincount(const int* __restrict__ dst,
                                                  int* __restrict__ bcnt, int E, int nbkt) {
    __shared__ int sh[MAXBKT];
    for (int i = threadIdx.x; i < nbkt; i += 256) sh[i] = 0;
    __syncthreads();
    for (long long e = (long long)blockIdx.x * 256 + threadIdx.x; e < E;
         e += (long long)gridDim.x * 256)
        atomicAdd(&sh[dst[e] >> BKT_SHIFT], 1);
    __syncthreads();
    for (int i = threadIdx.x; i < nbkt; i += 256)
        if (sh[i]) atomicAdd(&bcnt[i], sh[i]);
}

__global__ __launch_bounds__(1024) void k_bscan(const int* __restrict__ bcnt,
                                                int* __restrict__ bofs,
                                                int* __restrict__ bcur, int nbkt, int E) {
    __shared__ int sh[1024];
    int t = threadIdx.x;
    int v = (t < nbkt) ? bcnt[t] : 0;
    int x = v;
    sh[t] = x;
    __syncthreads();
    for (int o = 1; o < 1024; o <<= 1) {
        int y = (t >= o) ? sh[t - o] : 0;
        __syncthreads();
        x += y;
        sh[t] = x;
        __syncthreads();
    }
    if (t < nbkt) { bofs[t] = x - v; bcur[t] = x - v; }
    if (t == 0) bofs[nbkt] = E;
}

// bulk-reservation bin fill
__global__ __launch_bounds__(256) void k_binfill(const int* __restrict__ src,
                                                 const int* __restrict__ dst,
                                                 int* __restrict__ bcur,
                                                 unsigned* __restrict__ recs,
                                                 int E, int nbkt) {
    __shared__ unsigned stage[CH];          // 32 KB
    __shared__ unsigned short stageb[CH];   // 16 KB
    __shared__ int cnt[MAXBKT];             // 4 KB
    __shared__ int base[MAXBKT];            // 4 KB
    const int t = threadIdx.x;
    const long long c0 = (long long)blockIdx.x * CH;

    for (int i = t; i < nbkt; i += 256) cnt[i] = 0;
    __syncthreads();

    for (int k = 0; k < CH / 256; k++) {
        int i = k * 256 + t;
        long long e = c0 + i;
        if (e < E) {
            int d = dst[e];
            int b = d >> BKT_SHIFT;
            stage[i] = ((unsigned)(d & (BKT_NODES - 1)) << 17) | (unsigned)src[e];
            stageb[i] = (unsigned short)b;
            atomicAdd(&cnt[b], 1);
        }
    }
    __syncthreads();

    for (int i = t; i < nbkt; i += 256) {
        int c = cnt[i];
        base[i] = c ? atomicAdd(&bcur[i], c) : 0;
        cnt[i] = 0;
    }
    __syncthreads();

    for (int k = 0; k < CH / 256; k++) {
        int i = k * 256 + t;
        if (c0 + i < E) {
            int b = stageb[i];
            int p = base[b] + atomicAdd(&cnt[b], 1);
            recs[p] = stage[i];
        }
    }
}

__global__ __launch_bounds__(256) void k_deg_bins(const unsigned* __restrict__ recs,
                                                  const int* __restrict__ bofs,
                                                  int* __restrict__ deg, int n) {
    __shared__ int cnt[BKT_NODES];
    const int b = blockIdx.x, t = threadIdx.x;
    if (t < BKT_NODES) cnt[t] = 0;
    __syncthreads();
    const int beg = bofs[b], end = bofs[b + 1];
    for (int j = beg + t; j < end; j += 256)
        atomicAdd(&cnt[recs[j] >> 17], 1);
    __syncthreads();
    const int d0 = b << BKT_SHIFT;
    if (t < BKT_NODES && d0 + t < n) deg[d0 + t] = cnt[t];
}

__global__ void k_scan1(const int* __restrict__ deg, float* __restrict__ dinv,
                        int* __restrict__ ofs, int* __restrict__ sums, int n) {
    __shared__ int sh[256];
    const int t = threadIdx.x;
    const int i = blockIdx.x * 256 + t;
    int v = (i < n) ? deg[i] : 0;
    if (i < n) dinv[i] = rsqrtf((float)v + 1.0f);
    int x = v;
    sh[t] = x;
    __syncthreads();
    for (int o = 1; o < 256; o <<= 1) {
        int y = (t >= o) ? sh[t - o] : 0;
        __syncthreads();
        x += y;
        sh[t] = x;
        __syncthreads();
    }
    if (i < n) ofs[i] = x - v;
    if (t == 255) sums[blockIdx.x] = x;
}

__global__ void k_scan2(int* __restrict__ sums, int nb) {
    __shared__ int sh[512];
    const int t = threadIdx.x;
    int carry = 0;
    for (int base = 0; base < nb; base += 512) {
        int i = base + t;
        int v = (i < nb) ? sums[i] : 0;
        int x = v;
        sh[t] = x;
        __syncthreads();
        for (int o = 1; o < 512; o <<= 1) {
            int y = (t >= o) ? sh[t - o] : 0;
            __syncthreads();
            x += y;
            sh[t] = x;
            __syncthreads();
        }
        if (i < nb) sums[i] = x - v + carry;
        int tot = sh[511];
        __syncthreads();
        carry += tot;
    }
}

__global__ void k_scan3(int* __restrict__ ofs, const int* __restrict__ sums, int n, int E) {
    int i = blockIdx.x * 256 + threadIdx.x;
    if (i < n) ofs[i] += sums[blockIdx.x];
    if (i == 0) ofs[n] = E;
}

__global__ __launch_bounds__(256) void k_fill_bins(const unsigned* __restrict__ recs,
                                                   const int* __restrict__ bofs,
                                                   const int* __restrict__ ofs,
                                                   int* __restrict__ col, int n) {
    __shared__ int cur[BKT_NODES];
    const int b = blockIdx.x, t = threadIdx.x;
    const int d0 = b << BKT_SHIFT;
    if (t < BKT_NODES) cur[t] = (d0 + t < n) ? ofs[d0 + t] : 0;
    __syncthreads();
    const int beg = bofs[b], end = bofs[b + 1];
    for (int j = beg + t; j < end; j += 256) {
        unsigned r = recs[j];
        int p = atomicAdd(&cur[r >> 17], 1);
        col[p] = (int)(r & 0x1FFFF);
    }
}

// ---------------- W -> fp16 transposed: Wt[n][k] = W[k][n] ----------------
__global__ __launch_bounds__(256) void k_wt(const float* __restrict__ W,
                                            _Float16* __restrict__ Wt) {
    int i = blockIdx.x * 256 + threadIdx.x;   // 16384
    int k = i >> 7, c = i & 127;
    Wt[c * 128 + k] = (_Float16)W[k * 128 + c];
}

// ---------------- MFMA GEMM: ts[N x 128](fp16) = dinv[row] * ((relu?)in @ W) ----------------
// 64 rows/block, 4 waves, each wave: 16 rows x 128 cols via 8 16x16 tiles,
// K=128 in 4 chunks of 32. LDS rows padded +8 halves (272 B stride -> 4-bank
// offset per row -> only 2-way conflict on fragment ds_read_b128, free).
__global__ __launch_bounds__(256, 2) void k_gemm_mfma(const float* __restrict__ in,
                                                      const _Float16* __restrict__ Wt,
                                                      const float* __restrict__ dinv,
                                                      _Float16* __restrict__ out,
                                                      int n, int relu_in) {
    __shared__ _Float16 Al[64][136];   // 17.4 KB
    __shared__ _Float16 Bl[128][136];  // 34.8 KB
    const int t = threadIdx.x;
    const int row0 = blockIdx.x * 64;
    int nr = n - row0;
    if (nr > 64) nr = 64;

    // stage Wt (fp16, already [n][k]) via 16B loads
    for (int i = t; i < 128 * 16; i += 256) {
        int r = i >> 4, c8 = i & 15;
        *(half8v*)&Bl[r][c8 * 8] = *(const half8v*)&Wt[r * 128 + c8 * 8];
    }
    // stage A rows: fp32 -> fp16, optional relu
    for (int i = t; i < nr * 32; i += 256) {
        int r = i >> 5, c4 = i & 31;
        float4 v = *(const float4*)&in[(size_t)(row0 + r) * 128 + c4 * 4];
        if (relu_in) {
            v.x = fmaxf(v.x, 0.f); v.y = fmaxf(v.y, 0.f);
            v.z = fmaxf(v.z, 0.f); v.w = fmaxf(v.w, 0.f);
        }
        half4v hv;
        hv[0] = (_Float16)v.x; hv[1] = (_Float16)v.y;
        hv[2] = (_Float16)v.z; hv[3] = (_Float16)v.w;
        *(half4v*)&Al[r][c4 * 4] = hv;
    }
    __syncthreads();

    const int wave = t >> 6;        // 0..3 -> 16-row strip
    const int lane = t & 63;
    const int m0 = wave * 16;
    const int ml = lane & 15;       // m (A) / n (B) / col (D) within tile
    const int quad = lane >> 4;     // k-octet selector; D row group

    float4v acc[8] = {};
#pragma unroll
    for (int kc = 0; kc < 4; kc++) {
        half8v a = *(const half8v*)&Al[m0 + ml][kc * 32 + quad * 8];
#pragma unroll
        for (int nt = 0; nt < 8; nt++) {
            half8v b = *(const half8v*)&Bl[nt * 16 + ml][kc * 32 + quad * 8];
            acc[nt] = __builtin_amdgcn_mfma_f32_16x16x32_f16(a, b, acc[nt], 0, 0, 0);
        }
    }

    // D: col = ml, row = quad*4 + reg
#pragma unroll
    for (int reg = 0; reg < 4; reg++) {
        int r = m0 + quad * 4 + reg;
        if (r < nr) {
            float dv = dinv[row0 + r];
#pragma unroll
            for (int nt = 0; nt < 8; nt++)
                out[(size_t)(row0 + r) * 128 + nt * 16 + ml] =
                    (_Float16)(acc[nt][reg] * dv);
        }
    }
}

// ---------------- CSR aggregation: out[d] = bias + dinv[d] * (ts[d] + sum_j ts[col[j]]) ----------------
__global__ __launch_bounds__(256) void k_agg_csr(const int* __restrict__ ofs,
                                                 const int* __restrict__ col,
                                                 const float* __restrict__ dinv,
                                                 const half4v* __restrict__ ts,  // rows of 32 half4
                                                 const float* __restrict__ bias,
                                                 float* __restrict__ out, int n) {
    int gid = blockIdx.x * 256 + threadIdx.x;
    int row = gid >> 5;
    int lane = gid & 31;
    if (row >= n) return;

    float dd = dinv[row];
    int beg = ofs[row];
    int end = ofs[row + 1];

    half4v sv = ts[(size_t)row * 32 + lane];
    float4 acc = make_float4((float)sv[0], (float)sv[1], (float)sv[2], (float)sv[3]);

    int j = beg;
    for (; j + 3 < end; j += 4) {
        int s0 = col[j], s1 = col[j + 1], s2 = col[j + 2], s3 = col[j + 3];
        half4v v0 = ts[(size_t)s0 * 32 + lane];
        half4v v1 = ts[(size_t)s1 * 32 + lane];
        half4v v2 = ts[(size_t)s2 * 32 + lane];
        half4v v3 = ts[(size_t)s3 * 32 + lane];
        acc.x += (float)v0[0] + (float)v1[0] + (float)v2[0] + (float)v3[0];
        acc.y += (float)v0[1] + (float)v1[1] + (float)v2[1] + (float)v3[1];
        acc.z += (float)v0[2] + (float)v1[2] + (float)v2[2] + (float)v3[2];
        acc.w += (float)v0[3] + (float)v1[3] + (float)v2[3] + (float)v3[3];
    }
    for (; j < end; j++) {
        half4v v = ts[(size_t)col[j] * 32 + lane];
        acc.x += (float)v[0];
        acc.y += (float)v[1];
        acc.z += (float)v[2];
        acc.w += (float)v[3];
    }

    float4 bv = *(const float4*)&bias[lane * 4];
    float4 o;
    o.x = bv.x + dd * acc.x;
    o.y = bv.y + dd * acc.y;
    o.z = bv.z + dd * acc.z;
    o.w = bv.w + dd * acc.w;
    *(float4*)&out[(size_t)row * 128 + lane * 4] = o;
}

extern "C" void kernel_launch(void* const* d_in, const int* in_sizes, int n_in,
                              void* d_out, int out_size, void* d_ws, size_t ws_size,
                              hipStream_t stream) {
    const int N = in_sizes[0] / 128;
    const int E = in_sizes[1] / 2;
    const float* x  = (const float*)d_in[0];
    const int*   ei = (const int*)d_in[1];
    const float* W1 = (const float*)d_in[2];
    const float* b1 = (const float*)d_in[3];
    const float* W2 = (const float*)d_in[4];
    const float* b2 = (const float*)d_in[5];

    const int* src = ei;
    const int* dst = ei + E;

    const int nb_n  = (N + 255) / 256;
    const int NBKT  = (N + BKT_NODES - 1) / BKT_NODES;

    // ---- workspace layout (16B-aligned fp16 blocks first) ----
    _Float16* t    = (_Float16*)d_ws;            // N*128
    _Float16* wt1  = t + (size_t)N * 128;        // 16384
    _Float16* wt2  = wt1 + 16384;                // 16384
    float*    dinv = (float*)(wt2 + 16384);      // N
    int*      ofs  = (int*)(dinv + N);           // N+1
    int*      deg  = ofs + N + 1;                // N
    int*      sums = deg + N;                    // nb_n (padded)
    unsigned* recs = (unsigned*)(sums + ((nb_n + 255) & ~255)); // E
    int*      col  = (int*)(recs + E);           // E
    int*      bofs = col + E;                    // NBKT+1
    int*      bcur = bofs + NBKT + 1;            // NBKT
    int*      bcnt = bcur + NBKT;                // NBKT

    float* h   = (float*)d_out;   // layer-1 hidden (fp32) lives in d_out
    float* out = (float*)d_out;

    const int nb_g = (N + 63) / 64;
    const int nb_a = (int)(((long long)N * 32 + 255) / 256);
    const int nb_c = (int)(((long long)E + CH - 1) / CH);

    // ---- weight prep + binning + CSR build (reused by both layers) ----
    k_wt<<<64, 256, 0, stream>>>(W1, wt1);
    k_wt<<<64, 256, 0, stream>>>(W2, wt2);
    hipMemsetAsync(bcnt, 0, (size_t)NBKT * 4, stream);
    k_bincount<<<256, 256, 0, stream>>>(dst, bcnt, E, NBKT);
    k_bscan<<<1, 1024, 0, stream>>>(bcnt, bofs, bcur, NBKT, E);
    k_binfill<<<nb_c, 256, 0, stream>>>(src, dst, bcur, recs, E, NBKT);
    k_deg_bins<<<NBKT, 256, 0, stream>>>(recs, bofs, deg, N);
    k_scan1<<<nb_n, 256, 0, stream>>>(deg, dinv, ofs, sums, N);
    k_scan2<<<1, 512, 0, stream>>>(sums, nb_n);
    k_scan3<<<nb_n, 256, 0, stream>>>(ofs, sums, N, E);
    k_fill_bins<<<NBKT, 256, 0, stream>>>(recs, bofs, ofs, col, N);

    // ---- layer 1: ts = dinv * (x@W1) ; h = b1 + dinv * (ts[d] + sum ts[col]) ----
    k_gemm_mfma<<<nb_g, 256, 0, stream>>>(x, wt1, dinv, t, N, 0);
    k_agg_csr<<<nb_a, 256, 0, stream>>>(ofs, col, dinv, (const half4v*)t, b1, h, N);

    // ---- layer 2: ts = dinv * (relu(h)@W2) ; out = b2 + dinv * (...) ----
    k_gemm_mfma<<<nb_g, 256, 0, stream>>>(h, wt2, dinv, t, N, 1);
    k_agg_csr<<<nb_a, 256, 0, stream>>>(ofs, col, dinv, (const half4v*)t, b2, out, N);
}